// Round 3
// baseline (89.742 us; speedup 1.0000x reference)
//
#include <hip/hip_runtime.h>
#include <hip/hip_bf16.h>

typedef __attribute__((ext_vector_type(8))) short short8;
typedef __attribute__((ext_vector_type(4))) float f32x4;

#define KB 16   // k-blocks per tile; per-block K-range = 65536/16 = 4096 rules = 16 hi

__device__ __forceinline__ ushort f2bf(float f) {
    union { float f; unsigned u; } v; v.f = f;
    unsigned r = v.u + 0x7FFF + ((v.u >> 16) & 1);   // RNE
    return (ushort)(r >> 16);
}

// Wb -> frag-ordered bf16: wbf[gs][lane][j], element = Wb[gs*32 + 8*(lane>>4)+j][lane&15]
// cols 0..7 = W, col 8 = b, cols 9..15 = 0.  gs = r/32 (2048 steps).
__global__ __launch_bounds__(256) void prep_wb(const float* __restrict__ W,
                                               const float* __restrict__ b,
                                               ushort* __restrict__ wbf)
{
    const int gid = blockIdx.x * 256 + threadIdx.x;   // 0..131071
    const int gs = gid >> 6, lane = gid & 63;
    const int c = lane & 15, kb4 = lane >> 4;
    const int r0 = gs * 32 + kb4 * 8;
    short8 sv;
    if (c < 8) {
        #pragma unroll
        for (int j = 0; j < 8; ++j) sv[j] = (short)f2bf(W[(size_t)(r0 + j) * 8 + c]);
    } else if (c == 8) {
        #pragma unroll
        for (int j = 0; j < 8; ++j) sv[j] = (short)f2bf(b[r0 + j]);
    } else {
        #pragma unroll
        for (int j = 0; j < 8; ++j) sv[j] = 0;
    }
    *reinterpret_cast<short8*>(wbf + (size_t)gid * 8) = sv;   // coalesced 16B store
}

// Block = (sample-tile of 16) x (k-block of 4096 rules). 4 waves, wave w owns hi
// sub-range [kb*16 + 4w, +4). No barriers in the main loop; waves independent.
__global__ __launch_bounds__(256) void fz_main(const float* __restrict__ x,
                                               const float* __restrict__ center,
                                               const float* __restrict__ sigma,
                                               const ushort* __restrict__ wbf,
                                               float* __restrict__ S)
{
    __shared__ float  mgs[16][32];      // memberships for the tile's 16 samples
    __shared__ ushort plf[8][64][8];    // frag-ordered pl (A-frags), 8 lo-steps
    __shared__ float  phs[16][KB];      // ph[sample][hi_local]

    const int t = threadIdx.x;
    const int tile = blockIdx.x >> 4;   // KB==16
    const int kb = blockIdx.x & 15;

    #pragma unroll
    for (int v = 0; v < 2; ++v) {       // 512 mg values, 2/thread
        int id = t + v * 256;
        int s = id >> 5, i = id & 31, m = i >> 2;
        float xv = x[(size_t)(tile * 16 + s) * 8 + m];
        float d = xv - center[i];
        float sg = sigma[i];
        mgs[s][i] = __expf(-d * d * 0.5f * sg * sg);
    }
    __syncthreads();
    #pragma unroll
    for (int u = 0; u < 16; ++u) {      // 4096 pl bf16 values, 16/thread
        int e = t * 16 + u;
        int ls = e >> 9, lane = (e >> 3) & 63, j = e & 7;
        int s = lane & 15;
        int lo = ls * 32 + (lane >> 4) * 8 + j;   // same k-map as prep_wb
        float pl = mgs[s][16 + (lo >> 6)] * mgs[s][20 + ((lo >> 4) & 3)]
                 * mgs[s][24 + ((lo >> 2) & 3)] * mgs[s][28 + (lo & 3)];
        ((ushort*)plf)[e] = f2bf(pl);
    }
    {                                   // 256 ph values, 1/thread (fp32, exact)
        int s = t >> 4, hl = t & 15;
        int hi = kb * KB + hl;
        phs[s][hl] = mgs[s][hi >> 6] * mgs[s][4 + ((hi >> 4) & 3)]
                   * mgs[s][8 + ((hi >> 2) & 3)] * mgs[s][12 + (hi & 3)];
    }
    __syncthreads();

    const int wv = t >> 6, lane = t & 63;
    short8 A[8];
    #pragma unroll
    for (int ls = 0; ls < 8; ++ls)      // wave's 8 A-frags, reused across all hi
        A[ls] = *reinterpret_cast<const short8*>(&plf[ls][lane][0]);

    f32x4 master = {0.f, 0.f, 0.f, 0.f};
    const int hi_base = kb * KB + wv * 4;
    #pragma unroll
    for (int hil = 0; hil < 4; ++hil) {
        const int hi = hi_base + hil;
        f32x4 d = {0.f, 0.f, 0.f, 0.f};
        const ushort* bp = wbf + ((size_t)hi * 512 + lane) * 8;
        #pragma unroll
        for (int ls = 0; ls < 8; ++ls) {
            short8 B = *reinterpret_cast<const short8*>(bp + (size_t)ls * 512);
            d = __builtin_amdgcn_mfma_f32_16x16x32_bf16(A[ls], B, d, 0, 0, 0);
        }
        const int srow = (lane >> 4) * 4;   // C/D: col=lane&15, row=4*(lane>>4)+r (m89)
        #pragma unroll
        for (int r = 0; r < 4; ++r)
            master[r] += phs[srow + r][wv * 4 + hil] * d[r];   // fold ph post-MFMA
    }

    const int ck = kb * 4 + wv;             // chunk 0..63
    float* sp = S + ((size_t)tile * 64 + ck) * 256;
    const int ebase = (lane >> 4) * 64 + (lane & 15);
    #pragma unroll
    for (int r = 0; r < 4; ++r)
        sp[ebase + 16 * r] = master[r];     // elem = row*16+col
}

__global__ __launch_bounds__(256) void fz_final(const float* __restrict__ x,
                                                const float* __restrict__ center,
                                                const float* __restrict__ sigma,
                                                const float* __restrict__ S,
                                                float* __restrict__ out, int N)
{
    int n = blockIdx.x * 256 + threadIdx.x;
    if (n >= N) return;
    float xv[8];
    #pragma unroll
    for (int m = 0; m < 8; ++m) xv[m] = x[(size_t)n * 8 + m];
    float denom = 1.f;
    #pragma unroll
    for (int m = 0; m < 8; ++m) {       // sum_r fg factorizes exactly (fp32)
        float ssum = 0.f;
        #pragma unroll
        for (int j = 0; j < 4; ++j) {
            float d = xv[m] - center[m * 4 + j];
            float sg = sigma[m * 4 + j];
            ssum += __expf(-d * d * 0.5f * sg * sg);
        }
        denom *= ssum;
    }
    const int tile = n >> 4, si = n & 15;
    const int off = (si >> 2) * 64 + (si & 3) * 16;  // row si within 16x16 tile
    float sc[9];
    #pragma unroll
    for (int c = 0; c < 9; ++c) sc[c] = 0.f;
    #pragma unroll 8
    for (int ch = 0; ch < 64; ++ch) {
        const float* p = S + ((size_t)tile * 64 + ch) * 256 + off;
        const float4 a  = *reinterpret_cast<const float4*>(p);
        const float4 bq = *reinterpret_cast<const float4*>(p + 4);
        sc[0] += a.x;  sc[1] += a.y;  sc[2] += a.z;  sc[3] += a.w;
        sc[4] += bq.x; sc[5] += bq.y; sc[6] += bq.z; sc[7] += bq.w;
        sc[8] += p[8];
    }
    float num = sc[8];
    #pragma unroll
    for (int m = 0; m < 8; ++m) num += xv[m] * sc[m];
    out[n] = num / denom;
}

extern "C" void kernel_launch(void* const* d_in, const int* in_sizes, int n_in,
                              void* d_out, int out_size, void* d_ws, size_t ws_size,
                              hipStream_t stream)
{
    const float* x      = (const float*)d_in[0];
    const float* center = (const float*)d_in[1];
    const float* sigma  = (const float*)d_in[2];
    const float* W      = (const float*)d_in[3];
    const float* b      = (const float*)d_in[4];
    float* out = (float*)d_out;
    const int N = in_sizes[0] / 8;          // 1024

    ushort* wbf = (ushort*)d_ws;                          // 2 MB frag-ordered Wb
    float*  S   = (float*)((char*)d_ws + (size_t)2 * 1024 * 1024);  // 4 MB partials

    prep_wb<<<512, 256, 0, stream>>>(W, b, wbf);
    fz_main<<<(N / 16) * KB, 256, 0, stream>>>(x, center, sigma, wbf, S);
    fz_final<<<(N + 255) / 256, 256, 0, stream>>>(x, center, sigma, S, out, N);
}

// Round 4
// 85.327 us; speedup vs baseline: 1.0517x; 1.0517x over previous
//
#include <hip/hip_runtime.h>

typedef __attribute__((ext_vector_type(8))) short short8;
typedef __attribute__((ext_vector_type(4))) float f32x4;

#define KB 16            // K-chunks; block covers 16 hi = 4096 rules
#define ROWP 16          // padded floats per S row (aligned float4 reads)

__device__ __forceinline__ ushort f2bf_rne(float f) {
    union { float f; unsigned u; } v; v.f = f;
    unsigned r = v.u + 0x7FFF + ((v.u >> 16) & 1);   // RNE
    return (ushort)(r >> 16);
}

// Block = (sample-tile of 16) x (k-chunk of 4096 rules). 4 waves, wave wv owns
// hi in [kb*16 + 4*wv, +4). B-frags built in-register from fp32 W/b (no prep).
__global__ __launch_bounds__(256) void fz_main(
    const float* __restrict__ x, const float* __restrict__ center,
    const float* __restrict__ sigma, const float* __restrict__ W,
    const float* __restrict__ b, float* __restrict__ S /*[KB][N][ROWP]*/, int N)
{
    __shared__ float  mgs[16][32];      // memberships, 16 samples x (8 dims x 4)
    __shared__ ushort plf[8][64][8];    // frag-ordered p_lo (A-frags), 8 lo-steps
    __shared__ float  phs[16][KB];      // ph[sample][hi_local], fp32 exact
    __shared__ float  red[4][16][9];    // cross-wave fold

    const int t = threadIdx.x;
    const int tile = blockIdx.x >> 4;   // KB==16
    const int kb = blockIdx.x & (KB - 1);

    #pragma unroll
    for (int v = 0; v < 2; ++v) {       // 512 mg values, 2/thread
        int id = t + v * 256;
        int s = id >> 5, i = id & 31, m = i >> 2;
        float xv = x[(size_t)(tile * 16 + s) * 8 + m];
        float d = xv - center[i];
        float sg = sigma[i];
        mgs[s][i] = __expf(-d * d * 0.5f * sg * sg);
    }
    __syncthreads();
    {   // A-frags: thread t writes 16 contiguous ushorts (2x ds_write_b128)
        short8 o0, o1;
        #pragma unroll
        for (int u = 0; u < 16; ++u) {
            int e = t * 16 + u;
            int ls = e >> 9, lane = (e >> 3) & 63, j = e & 7;
            int s = lane & 15;
            int lo = ls * 32 + (lane >> 4) * 8 + j;   // k-map: k = 8*(lane>>4)+j
            float pl = mgs[s][16 + (lo >> 6)] * mgs[s][20 + ((lo >> 4) & 3)]
                     * mgs[s][24 + ((lo >> 2) & 3)] * mgs[s][28 + (lo & 3)];
            if (u < 8) o0[u] = (short)f2bf_rne(pl);
            else       o1[u - 8] = (short)f2bf_rne(pl);
        }
        short8* dst = reinterpret_cast<short8*>(((ushort*)plf) + t * 16);
        dst[0] = o0; dst[1] = o1;
    }
    {   // 256 ph values, 1/thread
        int s = t >> 4, hl = t & 15;
        int hi = kb * KB + hl;
        phs[s][hl] = mgs[s][hi >> 6] * mgs[s][4 + ((hi >> 4) & 3)]
                   * mgs[s][8 + ((hi >> 2) & 3)] * mgs[s][12 + (hi & 3)];
    }
    __syncthreads();

    const int wv = t >> 6, lane = t & 63;
    const int c = lane & 15, kb4 = lane >> 4;
    short8 A[8];
    #pragma unroll
    for (int ls = 0; ls < 8; ++ls)      // wave's 8 A-frags, reused across all hi
        A[ls] = *reinterpret_cast<const short8*>(&plf[ls][lane][0]);

    // per-lane B source: W column c (stride 8) for c<8, b (stride 1) otherwise;
    // lanes c>8 load b harmlessly and are zeroed after packing (no exec div.)
    const float* src = (c < 8) ? (W + c) : b;
    const int stride = (c < 8) ? 8 : 1;
    const bool live = (c <= 8);

    f32x4 master = {0.f, 0.f, 0.f, 0.f};
    const int hi_base = kb * KB + wv * 4;
    #pragma unroll
    for (int hil = 0; hil < 4; ++hil) {
        const int hi = hi_base + hil;
        f32x4 d = {0.f, 0.f, 0.f, 0.f};
        #pragma unroll
        for (int ls = 0; ls < 8; ++ls) {
            const int rbase = hi * 256 + ls * 32 + kb4 * 8;  // same k-map as A
            unsigned u[8];
            #pragma unroll
            for (int j = 0; j < 8; ++j) {
                union { float f; unsigned v; } q;
                q.f = src[(size_t)(rbase + j) * stride];
                u[j] = q.v;
            }
            unsigned Bp[4];
            #pragma unroll
            for (int j2 = 0; j2 < 4; ++j2) {    // round-half-up bf16 pack
                unsigned lo16 = (u[2 * j2] + 0x8000u) >> 16;
                unsigned hi16 = (u[2 * j2 + 1] + 0x8000u) & 0xFFFF0000u;
                Bp[j2] = live ? (hi16 | lo16) : 0u;
            }
            short8 B = *reinterpret_cast<short8*>(&Bp[0]);
            d = __builtin_amdgcn_mfma_f32_16x16x32_bf16(A[ls], B, d, 0, 0, 0);
        }
        const int srow = kb4 * 4;   // C/D: col=lane&15, row=4*(lane>>4)+r (m89)
        #pragma unroll
        for (int r = 0; r < 4; ++r)
            master[r] += phs[srow + r][wv * 4 + hil] * d[r];  // fold ph, fp32
    }

    // fold the 4 waves (disjoint hi) in LDS, one compact store per block
    if (c < 9) {
        #pragma unroll
        for (int r = 0; r < 4; ++r)
            red[wv][kb4 * 4 + r][c] = master[r];
    }
    __syncthreads();
    if (t < 144) {
        int s = t / 9, cc = t % 9;
        float v = red[0][s][cc] + red[1][s][cc] + red[2][s][cc] + red[3][s][cc];
        S[((size_t)kb * N + tile * 16 + s) * ROWP + cc] = v;
    }
}

__global__ __launch_bounds__(256) void fz_final(
    const float* __restrict__ x, const float* __restrict__ center,
    const float* __restrict__ sigma, const float* __restrict__ S,
    float* __restrict__ out, int N)
{
    int n = blockIdx.x * 256 + threadIdx.x;
    if (n >= N) return;
    float xv[8];
    #pragma unroll
    for (int m = 0; m < 8; ++m) xv[m] = x[(size_t)n * 8 + m];
    float denom = 1.f;
    #pragma unroll
    for (int m = 0; m < 8; ++m) {       // sum_r fg factorizes exactly (fp32)
        float ssum = 0.f;
        #pragma unroll
        for (int j = 0; j < 4; ++j) {
            float d = xv[m] - center[m * 4 + j];
            float sg = sigma[m * 4 + j];
            ssum += expf(-d * d * 0.5f * sg * sg);
        }
        denom *= ssum;
    }
    float sc[9];
    #pragma unroll
    for (int cc = 0; cc < 9; ++cc) sc[cc] = 0.f;
    #pragma unroll
    for (int ch = 0; ch < KB; ++ch) {
        const float* p = S + ((size_t)ch * N + n) * ROWP;   // 64B-aligned row
        const float4 a  = *reinterpret_cast<const float4*>(p);
        const float4 bq = *reinterpret_cast<const float4*>(p + 4);
        sc[0] += a.x;  sc[1] += a.y;  sc[2] += a.z;  sc[3] += a.w;
        sc[4] += bq.x; sc[5] += bq.y; sc[6] += bq.z; sc[7] += bq.w;
        sc[8] += p[8];
    }
    float num = sc[8];
    #pragma unroll
    for (int m = 0; m < 8; ++m) num += xv[m] * sc[m];
    out[n] = num / denom;
}

extern "C" void kernel_launch(void* const* d_in, const int* in_sizes, int n_in,
                              void* d_out, int out_size, void* d_ws, size_t ws_size,
                              hipStream_t stream)
{
    const float* x      = (const float*)d_in[0];
    const float* center = (const float*)d_in[1];
    const float* sigma  = (const float*)d_in[2];
    const float* W      = (const float*)d_in[3];
    const float* b      = (const float*)d_in[4];
    float* out = (float*)d_out;
    const int N = in_sizes[0] / 8;          // 1024

    float* S = (float*)d_ws;                // KB*N*ROWP floats = 1 MB

    fz_main<<<(N / 16) * KB, 256, 0, stream>>>(x, center, sigma, W, b, S, N);
    fz_final<<<(N + 255) / 256, 256, 0, stream>>>(x, center, sigma, S, out, N);
}

// Round 5
// 76.673 us; speedup vs baseline: 1.1705x; 1.1129x over previous
//
#include <hip/hip_runtime.h>

typedef __attribute__((ext_vector_type(8))) short short8;
typedef __attribute__((ext_vector_type(4))) float f32x4;

#define KB 16            // K-chunks; block covers 16 hi = 4096 rules
#define ROWP 16          // padded floats per S row (aligned float4 reads)

// Block = (sample-tile of 16) x (k-chunk of 4096 rules). 4 waves, wave wv owns
// hi in [kb*16 + 4*wv, +4). B-frags built in-register from fp32 W/b.
__global__ __launch_bounds__(256) void fz_main(
    const float* __restrict__ x, const float* __restrict__ center,
    const float* __restrict__ sigma, const float* __restrict__ W,
    const float* __restrict__ b, float* __restrict__ S /*[KB][N][ROWP]*/, int N)
{
    __shared__ float  mgs[16][33];      // memberships (padded rows: no 16-way bank conflict)
    __shared__ float  pr[16][20];       // d6,d7 pair products (pad 20 -> 16B-aligned quads)
    __shared__ ushort plf[8][64][8];    // frag-ordered p_lo (A-frags), 8 lo-steps
    __shared__ float  phs[16][17];      // ph[sample][hi_local], fp32 exact (padded)
    __shared__ float  red[4][16][9];    // cross-wave fold

    const int t = threadIdx.x;
    const int tile = blockIdx.x >> 4;   // KB==16
    const int kb = blockIdx.x & (KB - 1);

    #pragma unroll
    for (int v = 0; v < 2; ++v) {       // 512 mg values, 2/thread
        int id = t + v * 256;
        int s = id >> 5, i = id & 31, m = i >> 2;
        float xv = x[(size_t)(tile * 16 + s) * 8 + m];
        float d = xv - center[i];
        float sg = sigma[i];
        mgs[s][i] = __expf(-d * d * 0.5f * sg * sg);
    }
    __syncthreads();
    {   // pair table pr[s][4*d6+d7] and ph values, 1 entry each per thread
        int s = t >> 4, a = t & 15;
        pr[s][a] = mgs[s][24 + (a >> 2)] * mgs[s][28 + (a & 3)];
        int hi = kb * KB + a;
        phs[s][a] = mgs[s][hi >> 6] * mgs[s][4 + ((hi >> 4) & 3)]
                  * mgs[s][8 + ((hi >> 2) & 3)] * mgs[s][12 + (hi & 3)];
    }
    __syncthreads();
    {   // A-frags: thread t builds 2 octets (16 ushorts, 2x ds_write_b128)
        const int ls = t >> 5;                       // lo-step, fixed per thread
        #pragma unroll
        for (int oct = 0; oct < 2; ++oct) {
            const int lane_e = (2 * t + oct) & 63;
            const int s = lane_e & 15;
            const int hi3 = lane_e >> 4;
            const int L0 = ls * 32 + hi3 * 8;        // lo = L0 + j, j = 0..7
            const float pqv = mgs[s][16 + (L0 >> 6)] * mgs[s][20 + ((L0 >> 4) & 3)];
            const int b7 = L0 & 8;
            const float4 r0 = *reinterpret_cast<const float4*>(&pr[s][b7]);
            const float4 r1 = *reinterpret_cast<const float4*>(&pr[s][b7 + 4]);
            float pv[8] = { pqv * r0.x, pqv * r0.y, pqv * r0.z, pqv * r0.w,
                            pqv * r1.x, pqv * r1.y, pqv * r1.z, pqv * r1.w };
            unsigned Pk[4];
            #pragma unroll
            for (int j2 = 0; j2 < 4; ++j2) {         // round-half-up bf16 pack
                union { float f; unsigned u; } a0, a1;
                a0.f = pv[2 * j2]; a1.f = pv[2 * j2 + 1];
                Pk[j2] = ((a0.u + 0x8000u) >> 16) | ((a1.u + 0x8000u) & 0xFFFF0000u);
            }
            *reinterpret_cast<short8*>(&plf[ls][lane_e][0]) =
                *reinterpret_cast<short8*>(&Pk[0]);
        }
    }
    __syncthreads();

    const int wv = t >> 6, lane = t & 63;
    const int c = lane & 15, kb4 = lane >> 4;
    short8 A[8];
    #pragma unroll
    for (int ls = 0; ls < 8; ++ls)      // wave's 8 A-frags, reused across all hi
        A[ls] = *reinterpret_cast<const short8*>(&plf[ls][lane][0]);

    // per-lane B source: W column c (stride 8) for c<8, b (stride 1) for c==8;
    // lanes c>8 load b harmlessly, zeroed at pack via mask (no exec divergence)
    const float* src = (c < 8) ? (W + c) : b;
    const int stride = (c < 8) ? 8 : 1;
    const unsigned lmask = (c <= 8) ? 0xFFFFFFFFu : 0u;

    const int hi_base = kb * KB + wv * 4;
    const float* p = src + (size_t)(hi_base * 256 + kb4 * 8) * stride;
    const ptrdiff_t s32 = (ptrdiff_t)32 * stride;

    float buf[2][8];
    #pragma unroll
    for (int j = 0; j < 8; ++j) buf[0][j] = p[j * stride];   // preload step 0

    f32x4 master = {0.f, 0.f, 0.f, 0.f};
    f32x4 d = {0.f, 0.f, 0.f, 0.f};
    #pragma unroll
    for (int step = 0; step < 32; ++step) {          // rows contiguous: +32/step
        const float* pn = p + s32;
        if (step < 31) {
            #pragma unroll
            for (int j = 0; j < 8; ++j) buf[(step + 1) & 1][j] = pn[j * stride];
        }
        const float* cu = buf[step & 1];
        unsigned Bp[4];
        #pragma unroll
        for (int j2 = 0; j2 < 4; ++j2) {             // round-half-up bf16 pack
            union { float f; unsigned u; } a0, a1;
            a0.f = cu[2 * j2]; a1.f = cu[2 * j2 + 1];
            Bp[j2] = (((a0.u + 0x8000u) >> 16) | ((a1.u + 0x8000u) & 0xFFFF0000u)) & lmask;
        }
        short8 B = *reinterpret_cast<short8*>(&Bp[0]);
        d = __builtin_amdgcn_mfma_f32_16x16x32_bf16(A[step & 7], B, d, 0, 0, 0);
        if ((step & 7) == 7) {
            const int hil = step >> 3;               // fold ph, reset d
            #pragma unroll
            for (int r = 0; r < 4; ++r)
                master[r] += phs[kb4 * 4 + r][wv * 4 + hil] * d[r];
            d = (f32x4){0.f, 0.f, 0.f, 0.f};
        }
        p = pn;
    }

    // fold the 4 waves (disjoint hi) in LDS, one compact store per block
    if (c < 9) {
        #pragma unroll
        for (int r = 0; r < 4; ++r)
            red[wv][kb4 * 4 + r][c] = master[r];
    }
    __syncthreads();
    if (t < 144) {
        int s = t / 9, cc = t % 9;
        float v = red[0][s][cc] + red[1][s][cc] + red[2][s][cc] + red[3][s][cc];
        S[((size_t)kb * N + tile * 16 + s) * ROWP + cc] = v;
    }
}

__global__ __launch_bounds__(64) void fz_final(
    const float* __restrict__ x, const float* __restrict__ center,
    const float* __restrict__ sigma, const float* __restrict__ S,
    float* __restrict__ out, int N)
{
    int n = blockIdx.x * 64 + threadIdx.x;
    if (n >= N) return;
    float xv[8];
    #pragma unroll
    for (int m = 0; m < 8; ++m) xv[m] = x[(size_t)n * 8 + m];
    float denom = 1.f;                  // computed first: exp overlaps S loads below
    #pragma unroll
    for (int m = 0; m < 8; ++m) {       // sum_r fg factorizes exactly (fp32)
        float ssum = 0.f;
        #pragma unroll
        for (int j = 0; j < 4; ++j) {
            float dd = xv[m] - center[m * 4 + j];
            float sg = sigma[m * 4 + j];
            ssum += __expf(-dd * dd * 0.5f * sg * sg);
        }
        denom *= ssum;
    }
    float sc[9];
    #pragma unroll
    for (int cc = 0; cc < 9; ++cc) sc[cc] = 0.f;
    #pragma unroll
    for (int ch = 0; ch < KB; ++ch) {
        const float* p = S + ((size_t)ch * N + n) * ROWP;   // 64B-aligned row
        const float4 a  = *reinterpret_cast<const float4*>(p);
        const float4 bq = *reinterpret_cast<const float4*>(p + 4);
        sc[0] += a.x;  sc[1] += a.y;  sc[2] += a.z;  sc[3] += a.w;
        sc[4] += bq.x; sc[5] += bq.y; sc[6] += bq.z; sc[7] += bq.w;
        sc[8] += p[8];
    }
    float num = sc[8];
    #pragma unroll
    for (int m = 0; m < 8; ++m) num += xv[m] * sc[m];
    out[n] = num / denom;
}

extern "C" void kernel_launch(void* const* d_in, const int* in_sizes, int n_in,
                              void* d_out, int out_size, void* d_ws, size_t ws_size,
                              hipStream_t stream)
{
    const float* x      = (const float*)d_in[0];
    const float* center = (const float*)d_in[1];
    const float* sigma  = (const float*)d_in[2];
    const float* W      = (const float*)d_in[3];
    const float* b      = (const float*)d_in[4];
    float* out = (float*)d_out;
    const int N = in_sizes[0] / 8;          // 1024

    float* S = (float*)d_ws;                // KB*N*ROWP floats = 1 MB

    fz_main<<<(N / 16) * KB, 256, 0, stream>>>(x, center, sigma, W, b, S, N);
    fz_final<<<(N + 63) / 64, 64, 0, stream>>>(x, center, sigma, S, out, N);
}